// Round 6
// baseline (936.465 us; speedup 1.0000x reference)
//
#include <hip/hip_runtime.h>
#include <hip/hip_fp16.h>

#define DN 5
#define DE 4
#define DM 10
#define NB 2048               // hist/scatter blocks
#define BKT_SH 8              // bucket = dst >> 8  (256 nodes / bucket)
#define BKT_NODES 256
#define MAXBKT 1024           // LDS hist capacity (nbk=782 for N=200k)

typedef float        f4  __attribute__((ext_vector_type(4)));
typedef unsigned int u4v __attribute__((ext_vector_type(4)));

static __device__ __forceinline__ float2 h2f(unsigned u) {
    __half2 h = *reinterpret_cast<__half2*>(&u);
    return make_float2(__low2float(h), __high2float(h));
}
static __device__ __forceinline__ unsigned f2h(float a, float b) {
    __half2 h = __floats2half2_rn(a, b);
    return *reinterpret_cast<unsigned*>(&h);
}

// ---------------------------------------------------------------------------
// H: fused f16 node-pack + per-block bucket histogram.
//    naph[n] = {h2(a0,a1), h2(a2,a3), h2(a4,0), 0}  (16B, 3.2MB table)
// ---------------------------------------------------------------------------
__global__ __launch_bounds__(256) void hist_pack_kernel(
    const int* __restrict__ ei, const float* __restrict__ node_attr,
    u4v* __restrict__ naph, unsigned* __restrict__ cnt,
    int E, int chunk, int nbk, int N)
{
    __shared__ unsigned hist[MAXBKT];
    int t = threadIdx.x, b = blockIdx.x;

    int n = b * 256 + t;
    if (n < N) {
        const float* r = node_attr + (size_t)n * DN;
        u4v v;
        v.x = f2h(r[0], r[1]);
        v.y = f2h(r[2], r[3]);
        v.z = f2h(r[4], 0.f);
        v.w = 0u;
        naph[n] = v;
    }

    for (int j = t; j < nbk; j += 256) hist[j] = 0;
    __syncthreads();

    int e0 = b * chunk, e1 = min(E, e0 + chunk);
    for (int i = e0 + t; i < e1; i += 256) {
        int d = __builtin_nontemporal_load(ei + (size_t)E + i);
        atomicAdd(&hist[d >> BKT_SH], 1u);
    }
    __syncthreads();
    for (int j = t; j < nbk; j += 256)
        cnt[(size_t)j * NB + b] = hist[j];
}

// ---------------------------------------------------------------------------
// R: per-bucket row scan: cnt[j][0..NB-1] -> exclusive prefix; rowtotal[j]=sum
// ---------------------------------------------------------------------------
__global__ __launch_bounds__(256) void scan_rows_kernel(
    unsigned* __restrict__ cnt, unsigned* __restrict__ rowtotal)
{
    __shared__ unsigned lds[256];
    int j = blockIdx.x, t = threadIdx.x;
    unsigned* row = cnt + (size_t)j * NB;

    unsigned v[8], s = 0;
#pragma unroll
    for (int u = 0; u < 8; ++u) { v[u] = row[t * 8 + u]; s += v[u]; }
    lds[t] = s; __syncthreads();
#pragma unroll
    for (int o = 1; o < 256; o <<= 1) {
        unsigned add = (t >= o) ? lds[t - o] : 0u;
        __syncthreads();
        lds[t] += add;
        __syncthreads();
    }
    unsigned excl = lds[t] - s;
#pragma unroll
    for (int u = 0; u < 8; ++u) { row[t * 8 + u] = excl; excl += v[u]; }
    if (t == 255) rowtotal[j] = lds[255];
}

// ---------------------------------------------------------------------------
// B: exclusive scan of rowtotal[0..nbk-1] -> gbase[0..nbk] (gbase[nbk]=E)
// ---------------------------------------------------------------------------
__global__ __launch_bounds__(1024) void scan_base_kernel(
    const unsigned* __restrict__ rowtotal, unsigned* __restrict__ gbase,
    int nbk, int E)
{
    __shared__ unsigned lds[1024];
    int t = threadIdx.x;
    unsigned v = (t < nbk) ? rowtotal[t] : 0u;
    lds[t] = v; __syncthreads();
#pragma unroll
    for (int o = 1; o < 1024; o <<= 1) {
        unsigned add = (t >= o) ? lds[t - o] : 0u;
        __syncthreads();
        lds[t] += add;
        __syncthreads();
    }
    unsigned excl = lds[t] - v;
    if (t < nbk)       gbase[t] = excl;
    else if (t == nbk) gbase[t] = (unsigned)E;
}

// ---------------------------------------------------------------------------
// S: scatter edges to bucket-sorted 32B self-contained records:
//    rec[2p]   = (dstlow, h2(sa0,sa1), h2(sa2,sa3), h2(sa4,_))
//    rec[2p+1] = (h2(e0,e1), h2(e2,e3), 0, 0)
//    napack_h gather hits the 3.2MB L2-resident table.
// ---------------------------------------------------------------------------
__global__ __launch_bounds__(256) void scatter_kernel(
    const int* __restrict__ ei, const float* __restrict__ edge_attr,
    const unsigned* __restrict__ cnt, const unsigned* __restrict__ gbase,
    const u4v* __restrict__ naph,
    f4* __restrict__ rec, int E, int chunk, int nbk)
{
    __shared__ unsigned woff[MAXBKT];
    int t = threadIdx.x, b = blockIdx.x;
    for (int j = t; j < nbk; j += 256)
        woff[j] = gbase[j] + cnt[(size_t)j * NB + b];
    __syncthreads();

    int e0 = b * chunk, e1 = min(E, e0 + chunk);
    for (int i0 = e0 + t; i0 < e1; i0 += 4 * 256) {
        int s[4], d[4]; f4 ea[4]; bool act[4];
#pragma unroll
        for (int u = 0; u < 4; ++u) {
            int i = i0 + u * 256;
            act[u] = (i < e1);
            if (act[u]) {
                s[u]  = __builtin_nontemporal_load(ei + i);
                d[u]  = __builtin_nontemporal_load(ei + (size_t)E + i);
                ea[u] = __builtin_nontemporal_load(
                            reinterpret_cast<const f4*>(edge_attr) + i);
            }
        }
        u4v nap[4];
#pragma unroll
        for (int u = 0; u < 4; ++u)
            if (act[u]) nap[u] = naph[s[u]];        // cached (L2-resident)
#pragma unroll
        for (int u = 0; u < 4; ++u) {
            if (!act[u]) continue;
            unsigned p = atomicAdd(&woff[d[u] >> BKT_SH], 1u);
            f4 r0, r1;
            r0.x = __uint_as_float((unsigned)(d[u] & 255));
            r0.y = __uint_as_float(nap[u].x);
            r0.z = __uint_as_float(nap[u].y);
            r0.w = __uint_as_float(nap[u].z);
            r1.x = __uint_as_float(f2h(ea[u].x, ea[u].y));
            r1.y = __uint_as_float(f2h(ea[u].z, ea[u].w));
            r1.z = 0.f; r1.w = 0.f;
            __builtin_nontemporal_store(r0, rec + 2 * (size_t)p);
            __builtin_nontemporal_store(r1, rec + 2 * (size_t)p + 1);
        }
    }
}

// ---------------------------------------------------------------------------
// G: per-(bucket,split) gather — PURE STREAMING (records are self-contained).
//    Unpack f16, both projections in-register, LDS f32 atomic accumulate,
//    contiguous partial tile write.
// ---------------------------------------------------------------------------
__global__ __launch_bounds__(256) void gather_kernel(
    const f4* __restrict__ rec, const unsigned* __restrict__ gbase,
    const u4v* __restrict__ naph,
    const float* __restrict__ w_mpl, const float* __restrict__ b_mpl,
    float* __restrict__ xpart, size_t xstride,
    int E, int N, int nbk, int nsplit)
{
    __shared__ float acc[BKT_NODES * DM];      // 10 KB
    __shared__ float pdl[BKT_NODES * 12];      // 12 KB (48B rows)
    __shared__ float sws[50];                  // W_src
    __shared__ float swe[40];                  // W_edge

    int t = threadIdx.x;
    int j  = blockIdx.x / nsplit;
    int sp = blockIdx.x - j * nsplit;
    int nb0 = j * BKT_NODES;

    if (t < 50)       sws[t] = w_mpl[t];
    else if (t < 90)  swe[t - 50] = w_mpl[100 + (t - 50)];

    for (int i = t; i < BKT_NODES * DM; i += 256) acc[i] = 0.f;

    // stage dst-projection tile (bias folded in): one row per thread
    {
        int n = nb0 + t;
        float a0 = 0.f, a1 = 0.f, a2 = 0.f, a3 = 0.f, a4 = 0.f;
        if (n < N) {
            u4v v = naph[n];
            float2 p01 = h2f(v.x), p23 = h2f(v.y), p4 = h2f(v.z);
            a0 = p01.x; a1 = p01.y; a2 = p23.x; a3 = p23.y; a4 = p4.x;
        }
#pragma unroll
        for (int q = 0; q < DM; ++q) {
            float v = b_mpl[q];
            v = fmaf(a0, w_mpl[50 + q], v);
            v = fmaf(a1, w_mpl[60 + q], v);
            v = fmaf(a2, w_mpl[70 + q], v);
            v = fmaf(a3, w_mpl[80 + q], v);
            v = fmaf(a4, w_mpl[90 + q], v);
            pdl[t * 12 + q] = v;
        }
    }
    __syncthreads();

    unsigned start = gbase[j];
    unsigned end   = gbase[j + 1];
    unsigned blen  = end - start;
    unsigned csz   = (blen + nsplit - 1) / nsplit;
    unsigned ss    = start + (unsigned)sp * csz;
    unsigned se    = min(end, ss + csz);

    for (unsigned i0 = ss + t; i0 < se; i0 += 4u * 256u) {
        f4 r0[4], r1[4]; bool act[4];
#pragma unroll
        for (int u = 0; u < 4; ++u) {
            unsigned i = i0 + (unsigned)u * 256u;
            act[u] = (i < se);
            if (act[u]) {
                r0[u] = __builtin_nontemporal_load(rec + 2 * (size_t)i);
                r1[u] = __builtin_nontemporal_load(rec + 2 * (size_t)i + 1);
            }
        }
#pragma unroll
        for (int u = 0; u < 4; ++u) {
            if (!act[u]) continue;
            int dl = (int)__float_as_uint(r0[u].x);
            float2 s01 = h2f(__float_as_uint(r0[u].y));
            float2 s23 = h2f(__float_as_uint(r0[u].z));
            float2 s4_ = h2f(__float_as_uint(r0[u].w));
            float2 e01 = h2f(__float_as_uint(r1[u].x));
            float2 e23 = h2f(__float_as_uint(r1[u].y));
            float a0 = s01.x, a1 = s01.y, a2 = s23.x, a3 = s23.y, a4 = s4_.x;
            float e0 = e01.x, e1 = e01.y, e2 = e23.x, e3 = e23.y;

            const float* pr = &pdl[dl * 12];
            float4 p0 = *reinterpret_cast<const float4*>(pr);
            float4 p1 = *reinterpret_cast<const float4*>(pr + 4);
            float2 p2 = *reinterpret_cast<const float2*>(pr + 8);
            float m[DM] = {p0.x, p0.y, p0.z, p0.w, p1.x, p1.y, p1.z, p1.w, p2.x, p2.y};
#pragma unroll
            for (int q = 0; q < DM; ++q) {
                float v = m[q];
                v = fmaf(a0, sws[q],      v);
                v = fmaf(a1, sws[10 + q], v);
                v = fmaf(a2, sws[20 + q], v);
                v = fmaf(a3, sws[30 + q], v);
                v = fmaf(a4, sws[40 + q], v);
                v = fmaf(e0, swe[q],      v);
                v = fmaf(e1, swe[10 + q], v);
                v = fmaf(e2, swe[20 + q], v);
                v = fmaf(e3, swe[30 + q], v);
                if (v > 0.f) atomicAdd(&acc[dl * DM + q], v);  // ds_add_f32
            }
        }
    }
    __syncthreads();

    float* dst = xpart + (size_t)sp * xstride + (size_t)nb0 * DM;
    for (int i = t; i < BKT_NODES * DM; i += 256)
        __builtin_nontemporal_store(acc[i], dst + i);
}

// ---------------------------------------------------------------------------
// C: combine partials + node-MLP head + wave-segmented pooling into gacc
// ---------------------------------------------------------------------------
__global__ __launch_bounds__(256) void combine_kernel(
    const float* __restrict__ xpart, size_t xstride,
    const int* __restrict__ batch,
    const float* __restrict__ w1, const float* __restrict__ b1,
    const float* __restrict__ w2, const float* __restrict__ b2,
    float* __restrict__ gacc, int N, int nsplit)
{
    __shared__ float s1[100], sb1[10], s2[50], sb2[5];
    int t = threadIdx.x;
    if (t < 100)      s1[t] = w1[t];
    else if (t < 110) sb1[t - 100] = b1[t - 100];
    else if (t < 160) s2[t - 110] = w2[t - 110];
    else if (t < 165) sb2[t - 160] = b2[t - 160];
    __syncthreads();

    int n = blockIdx.x * blockDim.x + t;
    bool valid = (n < N);
    int g = 0x7fffffff;
    float h2[5] = {0.f, 0.f, 0.f, 0.f, 0.f};

    if (valid) {
        float x[DM];
#pragma unroll
        for (int q = 0; q < DM; ++q) x[q] = 0.f;
        for (int sp = 0; sp < nsplit; ++sp) {
            const float2* row = reinterpret_cast<const float2*>(
                xpart + (size_t)sp * xstride + (size_t)n * DM);
#pragma unroll
            for (int h = 0; h < 5; ++h) {
                float2 v = row[h];
                x[2 * h] += v.x; x[2 * h + 1] += v.y;
            }
        }

        float h1[10];
#pragma unroll
        for (int q = 0; q < 10; ++q) h1[q] = sb1[q];
#pragma unroll
        for (int k = 0; k < 10; ++k)
#pragma unroll
            for (int q = 0; q < 10; ++q) h1[q] = fmaf(x[k], s1[k * 10 + q], h1[q]);
#pragma unroll
        for (int q = 0; q < 10; ++q) h1[q] = fmaxf(h1[q], 0.f);
#pragma unroll
        for (int q = 0; q < 5; ++q) h2[q] = sb2[q];
#pragma unroll
        for (int k = 0; k < 10; ++k)
#pragma unroll
            for (int q = 0; q < 5; ++q) h2[q] = fmaf(h1[k], s2[k * 5 + q], h2[q]);
#pragma unroll
        for (int q = 0; q < 5; ++q) h2[q] = fmaxf(h2[q], 0.f);
        g = batch[n];
    }

    int lane = t & 63;
#pragma unroll
    for (int o = 1; o < 64; o <<= 1) {
        int go = __shfl_down(g, o);
        float v0 = __shfl_down(h2[0], o);
        float v1 = __shfl_down(h2[1], o);
        float v2 = __shfl_down(h2[2], o);
        float v3 = __shfl_down(h2[3], o);
        float v4 = __shfl_down(h2[4], o);
        if (lane + o < 64 && go == g) {
            h2[0] += v0; h2[1] += v1; h2[2] += v2; h2[3] += v3; h2[4] += v4;
        }
    }
    int gp = __shfl_up(g, 1);
    bool head = (lane == 0) || (gp != g);
    if (head && g != 0x7fffffff) {
#pragma unroll
        for (int q = 0; q < 5; ++q)
            if (h2[q] != 0.f) unsafeAtomicAdd(&gacc[(size_t)g * 5 + q], h2[q]);
    }
}

// ---------------------------------------------------------------------------
// k4: per-graph head
// ---------------------------------------------------------------------------
__global__ __launch_bounds__(256) void graph_head_kernel(
    const float* __restrict__ gacc,
    const float* __restrict__ w3, const float* __restrict__ b3,
    const float* __restrict__ w4, const float* __restrict__ b4,
    float* __restrict__ out, int G)
{
    __shared__ float s3[25], sb3[5], s4[5], sb4[1];
    int t = threadIdx.x;
    if (t < 25)       s3[t] = w3[t];
    else if (t < 30)  sb3[t - 25] = b3[t - 25];
    else if (t < 35)  s4[t - 30] = w4[t - 30];
    else if (t == 35) sb4[0] = b4[0];
    __syncthreads();

    int g = blockIdx.x * blockDim.x + t;
    if (g >= G) return;

    float x[5];
#pragma unroll
    for (int k = 0; k < 5; ++k) x[k] = gacc[(size_t)g * 5 + k];

    float o = sb4[0];
#pragma unroll
    for (int q = 0; q < 5; ++q) {
        float h = sb3[q];
#pragma unroll
        for (int k = 0; k < 5; ++k) h = fmaf(x[k], s3[k * 5 + q], h);
        h = fmaxf(h, 0.f);
        o = fmaf(h, s4[q], o);
    }
    out[g] = o;
}

// ---------------------------------------------------------------------------
extern "C" void kernel_launch(void* const* d_in, const int* in_sizes, int n_in,
                              void* d_out, int out_size, void* d_ws, size_t ws_size,
                              hipStream_t stream)
{
    const int*   ei        = (const int*)d_in[0];
    const float* node_attr = (const float*)d_in[1];
    const float* edge_attr = (const float*)d_in[2];
    const int*   batch     = (const int*)d_in[3];
    const float* w_mpl = (const float*)d_in[5];
    const float* b_mpl = (const float*)d_in[6];
    const float* w1    = (const float*)d_in[7];
    const float* b1    = (const float*)d_in[8];
    const float* w2    = (const float*)d_in[9];
    const float* b2    = (const float*)d_in[10];
    const float* w3    = (const float*)d_in[11];
    const float* b3    = (const float*)d_in[12];
    const float* w4    = (const float*)d_in[13];
    const float* b4    = (const float*)d_in[14];
    float* out = (float*)d_out;

    const int E = in_sizes[0] / 2;
    const int N = in_sizes[1] / DN;
    const int G = out_size;

    const int nbk   = (N + BKT_NODES - 1) / BKT_NODES;     // 782
    const int chunk = (E + NB - 1) / NB;                   // 3125

    // workspace layout (xpart aliases cnt: cnt is dead once scatter completes)
    char* p = (char*)d_ws;
    f4*       rec      = (f4*)p;       p += (size_t)E * 32;
    u4v*      naph     = (u4v*)p;      p += (size_t)N * 16;
    unsigned* rowtotal = (unsigned*)p; p += ((size_t)nbk * 4 + 15) & ~15ull;
    unsigned* gbase    = (unsigned*)p; p += ((size_t)(nbk + 1) * 4 + 15) & ~15ull;
    float*    gacc     = (float*)p;    p += (size_t)G * 5 * 4;
    unsigned* cnt      = (unsigned*)p;
    float*    xpart    = (float*)p;    // same base as cnt (sequential reuse)
    size_t cnt_bytes = (size_t)nbk * NB * 4;

    // pick nsplit per available workspace (deterministic in ws_size)
    size_t used = (size_t)((char*)cnt - (char*)d_ws);
    size_t xstride = (size_t)nbk * BKT_NODES * DM;         // floats per split
    int nsplit = 8;
    while (nsplit > 1 &&
           used + ((cnt_bytes > (size_t)nsplit * xstride * 4) ? cnt_bytes
                                                              : (size_t)nsplit * xstride * 4) > ws_size)
        nsplit >>= 1;

    hipMemsetAsync(gacc, 0, (size_t)G * 5 * 4, stream);

    hist_pack_kernel<<<NB, 256, 0, stream>>>(ei, node_attr, naph, cnt, E, chunk, nbk, N);
    scan_rows_kernel<<<nbk, 256, 0, stream>>>(cnt, rowtotal);
    scan_base_kernel<<<1, 1024, 0, stream>>>(rowtotal, gbase, nbk, E);
    scatter_kernel<<<NB, 256, 0, stream>>>(ei, edge_attr, cnt, gbase, naph, rec, E, chunk, nbk);
    gather_kernel<<<nbk * nsplit, 256, 0, stream>>>(rec, gbase, naph, w_mpl, b_mpl,
                                                    xpart, xstride, E, N, nbk, nsplit);
    combine_kernel<<<nbk, 256, 0, stream>>>(xpart, xstride, batch, w1, b1, w2, b2, gacc, N, nsplit);
    graph_head_kernel<<<(G + 255) / 256, 256, 0, stream>>>(gacc, w3, b3, w4, b4, out, G);
}

// Round 7
// 587.008 us; speedup vs baseline: 1.5953x; 1.5953x over previous
//
#include <hip/hip_runtime.h>
#include <hip/hip_fp16.h>

#define DN 5
#define DE 4
#define DM 10
#define NB 2048               // hist/scatter blocks
#define BKT_SH 8              // bucket = dst >> 8  (256 nodes / bucket)
#define BKT_NODES 256
#define MAXBKT 1024           // LDS hist capacity (nbk=782 for N=200k)

// XCD-grouping permutation: blocks dispatch round-robin across 8 XCDs, so
// group same-XCD blocks contiguously inside each bucket's record region.
#define PERM(b) (((b) & 7) * (NB / 8) + ((b) >> 3))

typedef float        f4  __attribute__((ext_vector_type(4)));
typedef unsigned int u4v __attribute__((ext_vector_type(4)));

static __device__ __forceinline__ float2 h2f(unsigned u) {
    __half2 h = *reinterpret_cast<__half2*>(&u);
    return make_float2(__low2float(h), __high2float(h));
}
static __device__ __forceinline__ unsigned f2h(float a, float b) {
    __half2 h = __floats2half2_rn(a, b);
    return *reinterpret_cast<unsigned*>(&h);
}

// ---------------------------------------------------------------------------
// H: fused f16 node-pack + per-block bucket histogram.
//    naph[n] = {h2(a0,a1), h2(a2,a3), h2(a4,0), 0}  (16B, 3.2MB table)
// ---------------------------------------------------------------------------
__global__ __launch_bounds__(256) void hist_pack_kernel(
    const int* __restrict__ ei, const float* __restrict__ node_attr,
    u4v* __restrict__ naph, unsigned* __restrict__ cnt,
    int E, int chunk, int nbk, int N)
{
    __shared__ unsigned hist[MAXBKT];
    int t = threadIdx.x, b = blockIdx.x;

    int n = b * 256 + t;
    if (n < N) {
        const float* r = node_attr + (size_t)n * DN;
        u4v v;
        v.x = f2h(r[0], r[1]);
        v.y = f2h(r[2], r[3]);
        v.z = f2h(r[4], 0.f);
        v.w = 0u;
        naph[n] = v;
    }

    for (int j = t; j < nbk; j += 256) hist[j] = 0;
    __syncthreads();

    int e0 = b * chunk, e1 = min(E, e0 + chunk);
    for (int i = e0 + t; i < e1; i += 256) {
        int d = __builtin_nontemporal_load(ei + (size_t)E + i);
        atomicAdd(&hist[d >> BKT_SH], 1u);
    }
    __syncthreads();
    for (int j = t; j < nbk; j += 256)
        cnt[(size_t)j * NB + PERM(b)] = hist[j];
}

// ---------------------------------------------------------------------------
// R: per-bucket row scan: cnt[j][0..NB-1] -> exclusive prefix; rowtotal[j]=sum
//    (positions are already in XCD-grouped order)
// ---------------------------------------------------------------------------
__global__ __launch_bounds__(256) void scan_rows_kernel(
    unsigned* __restrict__ cnt, unsigned* __restrict__ rowtotal)
{
    __shared__ unsigned lds[256];
    int j = blockIdx.x, t = threadIdx.x;
    unsigned* row = cnt + (size_t)j * NB;

    unsigned v[8], s = 0;
#pragma unroll
    for (int u = 0; u < 8; ++u) { v[u] = row[t * 8 + u]; s += v[u]; }
    lds[t] = s; __syncthreads();
#pragma unroll
    for (int o = 1; o < 256; o <<= 1) {
        unsigned add = (t >= o) ? lds[t - o] : 0u;
        __syncthreads();
        lds[t] += add;
        __syncthreads();
    }
    unsigned excl = lds[t] - s;
#pragma unroll
    for (int u = 0; u < 8; ++u) { row[t * 8 + u] = excl; excl += v[u]; }
    if (t == 255) rowtotal[j] = lds[255];
}

// ---------------------------------------------------------------------------
// B: exclusive scan of rowtotal[0..nbk-1] -> gbase[0..nbk] (gbase[nbk]=E)
// ---------------------------------------------------------------------------
__global__ __launch_bounds__(1024) void scan_base_kernel(
    const unsigned* __restrict__ rowtotal, unsigned* __restrict__ gbase,
    int nbk, int E)
{
    __shared__ unsigned lds[1024];
    int t = threadIdx.x;
    unsigned v = (t < nbk) ? rowtotal[t] : 0u;
    lds[t] = v; __syncthreads();
#pragma unroll
    for (int o = 1; o < 1024; o <<= 1) {
        unsigned add = (t >= o) ? lds[t - o] : 0u;
        __syncthreads();
        lds[t] += add;
        __syncthreads();
    }
    unsigned excl = lds[t] - v;
    if (t < nbk)       gbase[t] = excl;
    else if (t == nbk) gbase[t] = (unsigned)E;
}

// ---------------------------------------------------------------------------
// S: scatter edges to bucket-sorted 32B self-contained records:
//    rec[2p]   = (dstlow, h2(sa0,sa1), h2(sa2,sa3), h2(sa4,_))
//    rec[2p+1] = (h2(e0,e1), h2(e2,e3), 0, 0)
//    CACHED stores (L2 write-merging); NT streaming loads keep naph resident.
// ---------------------------------------------------------------------------
__global__ __launch_bounds__(256) void scatter_kernel(
    const int* __restrict__ ei, const float* __restrict__ edge_attr,
    const unsigned* __restrict__ cnt, const unsigned* __restrict__ gbase,
    const u4v* __restrict__ naph,
    f4* __restrict__ rec, int E, int chunk, int nbk)
{
    __shared__ unsigned woff[MAXBKT];
    int t = threadIdx.x, b = blockIdx.x;
    for (int j = t; j < nbk; j += 256)
        woff[j] = gbase[j] + cnt[(size_t)j * NB + PERM(b)];
    __syncthreads();

    int e0 = b * chunk, e1 = min(E, e0 + chunk);
    for (int i0 = e0 + t; i0 < e1; i0 += 4 * 256) {
        int s[4], d[4]; f4 ea[4]; bool act[4];
#pragma unroll
        for (int u = 0; u < 4; ++u) {
            int i = i0 + u * 256;
            act[u] = (i < e1);
            if (act[u]) {
                s[u]  = __builtin_nontemporal_load(ei + i);
                d[u]  = __builtin_nontemporal_load(ei + (size_t)E + i);
                ea[u] = __builtin_nontemporal_load(
                            reinterpret_cast<const f4*>(edge_attr) + i);
            }
        }
        u4v nap[4];
#pragma unroll
        for (int u = 0; u < 4; ++u)
            if (act[u]) nap[u] = naph[s[u]];        // cached (L2-resident)
#pragma unroll
        for (int u = 0; u < 4; ++u) {
            if (!act[u]) continue;
            unsigned p = atomicAdd(&woff[d[u] >> BKT_SH], 1u);
            f4 r0, r1;
            r0.x = __uint_as_float((unsigned)(d[u] & 255));
            r0.y = __uint_as_float(nap[u].x);
            r0.z = __uint_as_float(nap[u].y);
            r0.w = __uint_as_float(nap[u].z);
            r1.x = __uint_as_float(f2h(ea[u].x, ea[u].y));
            r1.y = __uint_as_float(f2h(ea[u].z, ea[u].w));
            r1.z = 0.f; r1.w = 0.f;
            rec[2 * (size_t)p]     = r0;            // cached: L2 merges runs
            rec[2 * (size_t)p + 1] = r1;
        }
    }
}

// ---------------------------------------------------------------------------
// G: per-(bucket,split) gather — PURE STREAMING (records are self-contained).
//    Unpack f16, both projections in-register, LDS f32 atomic accumulate,
//    contiguous partial tile write.
// ---------------------------------------------------------------------------
__global__ __launch_bounds__(256) void gather_kernel(
    const f4* __restrict__ rec, const unsigned* __restrict__ gbase,
    const u4v* __restrict__ naph,
    const float* __restrict__ w_mpl, const float* __restrict__ b_mpl,
    float* __restrict__ xpart, size_t xstride,
    int E, int N, int nbk, int nsplit)
{
    __shared__ float acc[BKT_NODES * DM];      // 10 KB
    __shared__ float pdl[BKT_NODES * 12];      // 12 KB (48B rows)
    __shared__ float sws[50];                  // W_src
    __shared__ float swe[40];                  // W_edge

    int t = threadIdx.x;
    int j  = blockIdx.x / nsplit;
    int sp = blockIdx.x - j * nsplit;
    int nb0 = j * BKT_NODES;

    if (t < 50)       sws[t] = w_mpl[t];
    else if (t < 90)  swe[t - 50] = w_mpl[100 + (t - 50)];

    for (int i = t; i < BKT_NODES * DM; i += 256) acc[i] = 0.f;

    // stage dst-projection tile (bias folded in): one row per thread
    {
        int n = nb0 + t;
        float a0 = 0.f, a1 = 0.f, a2 = 0.f, a3 = 0.f, a4 = 0.f;
        if (n < N) {
            u4v v = naph[n];
            float2 p01 = h2f(v.x), p23 = h2f(v.y), p4 = h2f(v.z);
            a0 = p01.x; a1 = p01.y; a2 = p23.x; a3 = p23.y; a4 = p4.x;
        }
#pragma unroll
        for (int q = 0; q < DM; ++q) {
            float v = b_mpl[q];
            v = fmaf(a0, w_mpl[50 + q], v);
            v = fmaf(a1, w_mpl[60 + q], v);
            v = fmaf(a2, w_mpl[70 + q], v);
            v = fmaf(a3, w_mpl[80 + q], v);
            v = fmaf(a4, w_mpl[90 + q], v);
            pdl[t * 12 + q] = v;
        }
    }
    __syncthreads();

    unsigned start = gbase[j];
    unsigned end   = gbase[j + 1];
    unsigned blen  = end - start;
    unsigned csz   = (blen + nsplit - 1) / nsplit;
    unsigned ss    = start + (unsigned)sp * csz;
    unsigned se    = min(end, ss + csz);

    for (unsigned i0 = ss + t; i0 < se; i0 += 4u * 256u) {
        f4 r0[4], r1[4]; bool act[4];
#pragma unroll
        for (int u = 0; u < 4; ++u) {
            unsigned i = i0 + (unsigned)u * 256u;
            act[u] = (i < se);
            if (act[u]) {
                r0[u] = __builtin_nontemporal_load(rec + 2 * (size_t)i);
                r1[u] = __builtin_nontemporal_load(rec + 2 * (size_t)i + 1);
            }
        }
#pragma unroll
        for (int u = 0; u < 4; ++u) {
            if (!act[u]) continue;
            int dl = (int)__float_as_uint(r0[u].x);
            float2 s01 = h2f(__float_as_uint(r0[u].y));
            float2 s23 = h2f(__float_as_uint(r0[u].z));
            float2 s4_ = h2f(__float_as_uint(r0[u].w));
            float2 e01 = h2f(__float_as_uint(r1[u].x));
            float2 e23 = h2f(__float_as_uint(r1[u].y));
            float a0 = s01.x, a1 = s01.y, a2 = s23.x, a3 = s23.y, a4 = s4_.x;
            float e0 = e01.x, e1 = e01.y, e2 = e23.x, e3 = e23.y;

            const float* pr = &pdl[dl * 12];
            float4 p0 = *reinterpret_cast<const float4*>(pr);
            float4 p1 = *reinterpret_cast<const float4*>(pr + 4);
            float2 p2 = *reinterpret_cast<const float2*>(pr + 8);
            float m[DM] = {p0.x, p0.y, p0.z, p0.w, p1.x, p1.y, p1.z, p1.w, p2.x, p2.y};
#pragma unroll
            for (int q = 0; q < DM; ++q) {
                float v = m[q];
                v = fmaf(a0, sws[q],      v);
                v = fmaf(a1, sws[10 + q], v);
                v = fmaf(a2, sws[20 + q], v);
                v = fmaf(a3, sws[30 + q], v);
                v = fmaf(a4, sws[40 + q], v);
                v = fmaf(e0, swe[q],      v);
                v = fmaf(e1, swe[10 + q], v);
                v = fmaf(e2, swe[20 + q], v);
                v = fmaf(e3, swe[30 + q], v);
                if (v > 0.f) atomicAdd(&acc[dl * DM + q], v);  // ds_add_f32
            }
        }
    }
    __syncthreads();

    float* dst = xpart + (size_t)sp * xstride + (size_t)nb0 * DM;
    for (int i = t; i < BKT_NODES * DM; i += 256)
        __builtin_nontemporal_store(acc[i], dst + i);
}

// ---------------------------------------------------------------------------
// C: combine partials + node-MLP head + wave-segmented pooling into gacc
// ---------------------------------------------------------------------------
__global__ __launch_bounds__(256) void combine_kernel(
    const float* __restrict__ xpart, size_t xstride,
    const int* __restrict__ batch,
    const float* __restrict__ w1, const float* __restrict__ b1,
    const float* __restrict__ w2, const float* __restrict__ b2,
    float* __restrict__ gacc, int N, int nsplit)
{
    __shared__ float s1[100], sb1[10], s2[50], sb2[5];
    int t = threadIdx.x;
    if (t < 100)      s1[t] = w1[t];
    else if (t < 110) sb1[t - 100] = b1[t - 100];
    else if (t < 160) s2[t - 110] = w2[t - 110];
    else if (t < 165) sb2[t - 160] = b2[t - 160];
    __syncthreads();

    int n = blockIdx.x * blockDim.x + t;
    bool valid = (n < N);
    int g = 0x7fffffff;
    float h2[5] = {0.f, 0.f, 0.f, 0.f, 0.f};

    if (valid) {
        float x[DM];
#pragma unroll
        for (int q = 0; q < DM; ++q) x[q] = 0.f;
        for (int sp = 0; sp < nsplit; ++sp) {
            const float2* row = reinterpret_cast<const float2*>(
                xpart + (size_t)sp * xstride + (size_t)n * DM);
#pragma unroll
            for (int h = 0; h < 5; ++h) {
                float2 v = row[h];
                x[2 * h] += v.x; x[2 * h + 1] += v.y;
            }
        }

        float h1[10];
#pragma unroll
        for (int q = 0; q < 10; ++q) h1[q] = sb1[q];
#pragma unroll
        for (int k = 0; k < 10; ++k)
#pragma unroll
            for (int q = 0; q < 10; ++q) h1[q] = fmaf(x[k], s1[k * 10 + q], h1[q]);
#pragma unroll
        for (int q = 0; q < 10; ++q) h1[q] = fmaxf(h1[q], 0.f);
#pragma unroll
        for (int q = 0; q < 5; ++q) h2[q] = sb2[q];
#pragma unroll
        for (int k = 0; k < 10; ++k)
#pragma unroll
            for (int q = 0; q < 5; ++q) h2[q] = fmaf(h1[k], s2[k * 5 + q], h2[q]);
#pragma unroll
        for (int q = 0; q < 5; ++q) h2[q] = fmaxf(h2[q], 0.f);
        g = batch[n];
    }

    int lane = t & 63;
#pragma unroll
    for (int o = 1; o < 64; o <<= 1) {
        int go = __shfl_down(g, o);
        float v0 = __shfl_down(h2[0], o);
        float v1 = __shfl_down(h2[1], o);
        float v2 = __shfl_down(h2[2], o);
        float v3 = __shfl_down(h2[3], o);
        float v4 = __shfl_down(h2[4], o);
        if (lane + o < 64 && go == g) {
            h2[0] += v0; h2[1] += v1; h2[2] += v2; h2[3] += v3; h2[4] += v4;
        }
    }
    int gp = __shfl_up(g, 1);
    bool head = (lane == 0) || (gp != g);
    if (head && g != 0x7fffffff) {
#pragma unroll
        for (int q = 0; q < 5; ++q)
            if (h2[q] != 0.f) unsafeAtomicAdd(&gacc[(size_t)g * 5 + q], h2[q]);
    }
}

// ---------------------------------------------------------------------------
// k4: per-graph head
// ---------------------------------------------------------------------------
__global__ __launch_bounds__(256) void graph_head_kernel(
    const float* __restrict__ gacc,
    const float* __restrict__ w3, const float* __restrict__ b3,
    const float* __restrict__ w4, const float* __restrict__ b4,
    float* __restrict__ out, int G)
{
    __shared__ float s3[25], sb3[5], s4[5], sb4[1];
    int t = threadIdx.x;
    if (t < 25)       s3[t] = w3[t];
    else if (t < 30)  sb3[t - 25] = b3[t - 25];
    else if (t < 35)  s4[t - 30] = w4[t - 30];
    else if (t == 35) sb4[0] = b4[0];
    __syncthreads();

    int g = blockIdx.x * blockDim.x + t;
    if (g >= G) return;

    float x[5];
#pragma unroll
    for (int k = 0; k < 5; ++k) x[k] = gacc[(size_t)g * 5 + k];

    float o = sb4[0];
#pragma unroll
    for (int q = 0; q < 5; ++q) {
        float h = sb3[q];
#pragma unroll
        for (int k = 0; k < 5; ++k) h = fmaf(x[k], s3[k * 5 + q], h);
        h = fmaxf(h, 0.f);
        o = fmaf(h, s4[q], o);
    }
    out[g] = o;
}

// ---------------------------------------------------------------------------
extern "C" void kernel_launch(void* const* d_in, const int* in_sizes, int n_in,
                              void* d_out, int out_size, void* d_ws, size_t ws_size,
                              hipStream_t stream)
{
    const int*   ei        = (const int*)d_in[0];
    const float* node_attr = (const float*)d_in[1];
    const float* edge_attr = (const float*)d_in[2];
    const int*   batch     = (const int*)d_in[3];
    const float* w_mpl = (const float*)d_in[5];
    const float* b_mpl = (const float*)d_in[6];
    const float* w1    = (const float*)d_in[7];
    const float* b1    = (const float*)d_in[8];
    const float* w2    = (const float*)d_in[9];
    const float* b2    = (const float*)d_in[10];
    const float* w3    = (const float*)d_in[11];
    const float* b3    = (const float*)d_in[12];
    const float* w4    = (const float*)d_in[13];
    const float* b4    = (const float*)d_in[14];
    float* out = (float*)d_out;

    const int E = in_sizes[0] / 2;
    const int N = in_sizes[1] / DN;
    const int G = out_size;

    const int nbk   = (N + BKT_NODES - 1) / BKT_NODES;     // 782
    const int chunk = (E + NB - 1) / NB;                   // 3125

    // workspace layout (xpart aliases cnt: cnt is dead once scatter completes)
    char* p = (char*)d_ws;
    f4*       rec      = (f4*)p;       p += (size_t)E * 32;
    u4v*      naph     = (u4v*)p;      p += (size_t)N * 16;
    unsigned* rowtotal = (unsigned*)p; p += ((size_t)nbk * 4 + 15) & ~15ull;
    unsigned* gbase    = (unsigned*)p; p += ((size_t)(nbk + 1) * 4 + 15) & ~15ull;
    float*    gacc     = (float*)p;    p += (size_t)G * 5 * 4;
    unsigned* cnt      = (unsigned*)p;
    float*    xpart    = (float*)p;    // same base as cnt (sequential reuse)
    size_t cnt_bytes = (size_t)nbk * NB * 4;

    // pick nsplit per available workspace (deterministic in ws_size)
    size_t used = (size_t)((char*)cnt - (char*)d_ws);
    size_t xstride = (size_t)nbk * BKT_NODES * DM;         // floats per split
    int nsplit = 8;
    while (nsplit > 1 &&
           used + ((cnt_bytes > (size_t)nsplit * xstride * 4) ? cnt_bytes
                                                              : (size_t)nsplit * xstride * 4) > ws_size)
        nsplit >>= 1;

    hipMemsetAsync(gacc, 0, (size_t)G * 5 * 4, stream);

    hist_pack_kernel<<<NB, 256, 0, stream>>>(ei, node_attr, naph, cnt, E, chunk, nbk, N);
    scan_rows_kernel<<<nbk, 256, 0, stream>>>(cnt, rowtotal);
    scan_base_kernel<<<1, 1024, 0, stream>>>(rowtotal, gbase, nbk, E);
    scatter_kernel<<<NB, 256, 0, stream>>>(ei, edge_attr, cnt, gbase, naph, rec, E, chunk, nbk);
    gather_kernel<<<nbk * nsplit, 256, 0, stream>>>(rec, gbase, naph, w_mpl, b_mpl,
                                                    xpart, xstride, E, N, nbk, nsplit);
    combine_kernel<<<nbk, 256, 0, stream>>>(xpart, xstride, batch, w1, b1, w2, b2, gacc, N, nsplit);
    graph_head_kernel<<<(G + 255) / 256, 256, 0, stream>>>(gacc, w3, b3, w4, b4, out, G);
}

// Round 8
// 506.390 us; speedup vs baseline: 1.8493x; 1.1592x over previous
//
#include <hip/hip_runtime.h>
#include <hip/hip_fp16.h>

#define DN 5
#define DE 4
#define DM 10
#define NB 2048               // hist/scatter blocks
#define BKT_SH 8              // bucket = dst >> 8  (256 nodes / bucket)
#define BKT_NODES 256
#define MAXBKT 1024           // LDS hist capacity (nbk=782 for N=200k)

// XCD-grouping permutation: blocks dispatch round-robin across 8 XCDs, so
// group same-XCD blocks contiguously inside each bucket's record region.
#define PERM(b) (((b) & 7) * (NB / 8) + ((b) >> 3))

typedef float        f4  __attribute__((ext_vector_type(4)));
typedef unsigned int u4v __attribute__((ext_vector_type(4)));

static __device__ __forceinline__ float2 h2f(unsigned u) {
    __half2 h = *reinterpret_cast<__half2*>(&u);
    return make_float2(__low2float(h), __high2float(h));
}
static __device__ __forceinline__ unsigned f2h(float a, float b) {
    __half2 h = __floats2half2_rn(a, b);
    return *reinterpret_cast<unsigned*>(&h);
}

// ---------------------------------------------------------------------------
// H: fused f16 node-pack + per-block bucket histogram.
//    naph[n] = {h2(a0,a1), h2(a2,a3), h2(a4,0), 0}  (16B, 3.2MB table)
// ---------------------------------------------------------------------------
__global__ __launch_bounds__(256) void hist_pack_kernel(
    const int* __restrict__ ei, const float* __restrict__ node_attr,
    u4v* __restrict__ naph, unsigned* __restrict__ cnt,
    int E, int chunk, int nbk, int N)
{
    __shared__ unsigned hist[MAXBKT];
    int t = threadIdx.x, b = blockIdx.x;

    int n = b * 256 + t;
    if (n < N) {
        const float* r = node_attr + (size_t)n * DN;
        u4v v;
        v.x = f2h(r[0], r[1]);
        v.y = f2h(r[2], r[3]);
        v.z = f2h(r[4], 0.f);
        v.w = 0u;
        naph[n] = v;
    }

    for (int j = t; j < nbk; j += 256) hist[j] = 0;
    __syncthreads();

    int e0 = b * chunk, e1 = min(E, e0 + chunk);
    for (int i = e0 + t; i < e1; i += 256) {
        int d = __builtin_nontemporal_load(ei + (size_t)E + i);
        atomicAdd(&hist[d >> BKT_SH], 1u);
    }
    __syncthreads();
    for (int j = t; j < nbk; j += 256)
        cnt[(size_t)j * NB + PERM(b)] = hist[j];
}

// ---------------------------------------------------------------------------
// R: per-bucket row scan: cnt[j][0..NB-1] -> exclusive prefix; rowtotal[j]=sum
// ---------------------------------------------------------------------------
__global__ __launch_bounds__(256) void scan_rows_kernel(
    unsigned* __restrict__ cnt, unsigned* __restrict__ rowtotal)
{
    __shared__ unsigned lds[256];
    int j = blockIdx.x, t = threadIdx.x;
    unsigned* row = cnt + (size_t)j * NB;

    unsigned v[8], s = 0;
#pragma unroll
    for (int u = 0; u < 8; ++u) { v[u] = row[t * 8 + u]; s += v[u]; }
    lds[t] = s; __syncthreads();
#pragma unroll
    for (int o = 1; o < 256; o <<= 1) {
        unsigned add = (t >= o) ? lds[t - o] : 0u;
        __syncthreads();
        lds[t] += add;
        __syncthreads();
    }
    unsigned excl = lds[t] - s;
#pragma unroll
    for (int u = 0; u < 8; ++u) { row[t * 8 + u] = excl; excl += v[u]; }
    if (t == 255) rowtotal[j] = lds[255];
}

// ---------------------------------------------------------------------------
// B: exclusive scan of rowtotal[0..nbk-1] -> gbase[0..nbk] (gbase[nbk]=E)
// ---------------------------------------------------------------------------
__global__ __launch_bounds__(1024) void scan_base_kernel(
    const unsigned* __restrict__ rowtotal, unsigned* __restrict__ gbase,
    int nbk, int E)
{
    __shared__ unsigned lds[1024];
    int t = threadIdx.x;
    unsigned v = (t < nbk) ? rowtotal[t] : 0u;
    lds[t] = v; __syncthreads();
#pragma unroll
    for (int o = 1; o < 1024; o <<= 1) {
        unsigned add = (t >= o) ? lds[t - o] : 0u;
        __syncthreads();
        lds[t] += add;
        __syncthreads();
    }
    unsigned excl = lds[t] - v;
    if (t < nbk)       gbase[t] = excl;
    else if (t == nbk) gbase[t] = (unsigned)E;
}

// ---------------------------------------------------------------------------
// S: scatter edges to bucket-sorted 16B records:
//    rec[p] = { src | (dst&255)<<18 , h2(e0,e1), h2(e2,e3), 0 }
//    ONE 16B cached store per edge (L2 merges runs).
// ---------------------------------------------------------------------------
__global__ __launch_bounds__(256) void scatter_kernel(
    const int* __restrict__ ei, const float* __restrict__ edge_attr,
    const unsigned* __restrict__ cnt, const unsigned* __restrict__ gbase,
    u4v* __restrict__ rec, int E, int chunk, int nbk)
{
    __shared__ unsigned woff[MAXBKT];
    int t = threadIdx.x, b = blockIdx.x;
    for (int j = t; j < nbk; j += 256)
        woff[j] = gbase[j] + cnt[(size_t)j * NB + PERM(b)];
    __syncthreads();

    int e0 = b * chunk, e1 = min(E, e0 + chunk);
    for (int i0 = e0 + t; i0 < e1; i0 += 4 * 256) {
        int s[4], d[4]; f4 ea[4]; bool act[4];
#pragma unroll
        for (int u = 0; u < 4; ++u) {
            int i = i0 + u * 256;
            act[u] = (i < e1);
            if (act[u]) {
                s[u]  = __builtin_nontemporal_load(ei + i);
                d[u]  = __builtin_nontemporal_load(ei + (size_t)E + i);
                ea[u] = __builtin_nontemporal_load(
                            reinterpret_cast<const f4*>(edge_attr) + i);
            }
        }
#pragma unroll
        for (int u = 0; u < 4; ++u) {
            if (!act[u]) continue;
            unsigned p = atomicAdd(&woff[d[u] >> BKT_SH], 1u);
            u4v r;
            r.x = (unsigned)s[u] | ((unsigned)(d[u] & 255) << 18);
            r.y = f2h(ea[u].x, ea[u].y);
            r.z = f2h(ea[u].z, ea[u].w);
            r.w = 0u;
            rec[p] = r;                             // cached: L2 merges runs
        }
    }
}

// ---------------------------------------------------------------------------
// G: per-(bucket,split) gather. NT-stream 16B records, random naph[src]
//    gather vs the 3.2MB L2-resident table, both projections in-register,
//    LDS f32 atomic accumulate, contiguous partial tile write.
// ---------------------------------------------------------------------------
__global__ __launch_bounds__(256) void gather_kernel(
    const u4v* __restrict__ rec, const unsigned* __restrict__ gbase,
    const u4v* __restrict__ naph,
    const float* __restrict__ w_mpl, const float* __restrict__ b_mpl,
    float* __restrict__ xpart, size_t xstride,
    int E, int N, int nbk, int nsplit)
{
    __shared__ float acc[BKT_NODES * DM];      // 10 KB
    __shared__ float pdl[BKT_NODES * 12];      // 12 KB (48B rows)
    __shared__ float sws[50];                  // W_src
    __shared__ float swe[40];                  // W_edge

    int t = threadIdx.x;
    int j  = blockIdx.x / nsplit;
    int sp = blockIdx.x - j * nsplit;
    int nb0 = j * BKT_NODES;

    if (t < 50)       sws[t] = w_mpl[t];
    else if (t < 90)  swe[t - 50] = w_mpl[100 + (t - 50)];

    for (int i = t; i < BKT_NODES * DM; i += 256) acc[i] = 0.f;

    // stage dst-projection tile (bias folded in): one row per thread
    {
        int n = nb0 + t;
        float a0 = 0.f, a1 = 0.f, a2 = 0.f, a3 = 0.f, a4 = 0.f;
        if (n < N) {
            u4v v = naph[n];
            float2 p01 = h2f(v.x), p23 = h2f(v.y), p4 = h2f(v.z);
            a0 = p01.x; a1 = p01.y; a2 = p23.x; a3 = p23.y; a4 = p4.x;
        }
#pragma unroll
        for (int q = 0; q < DM; ++q) {
            float v = b_mpl[q];
            v = fmaf(a0, w_mpl[50 + q], v);
            v = fmaf(a1, w_mpl[60 + q], v);
            v = fmaf(a2, w_mpl[70 + q], v);
            v = fmaf(a3, w_mpl[80 + q], v);
            v = fmaf(a4, w_mpl[90 + q], v);
            pdl[t * 12 + q] = v;
        }
    }
    __syncthreads();

    unsigned start = gbase[j];
    unsigned end   = gbase[j + 1];
    unsigned blen  = end - start;
    unsigned csz   = (blen + nsplit - 1) / nsplit;
    unsigned ss    = start + (unsigned)sp * csz;
    unsigned se    = min(end, ss + csz);

    for (unsigned i0 = ss + t; i0 < se; i0 += 4u * 256u) {
        u4v r[4]; bool act[4];
#pragma unroll
        for (int u = 0; u < 4; ++u) {
            unsigned i = i0 + (unsigned)u * 256u;
            act[u] = (i < se);
            if (act[u]) r[u] = __builtin_nontemporal_load(rec + i);
        }
        u4v nap[4];
#pragma unroll
        for (int u = 0; u < 4; ++u)
            if (act[u]) nap[u] = naph[r[u].x & 0x3FFFFu];   // cached (L2-resident)
#pragma unroll
        for (int u = 0; u < 4; ++u) {
            if (!act[u]) continue;
            int dl = (int)((r[u].x >> 18) & 255u);
            float2 s01 = h2f(nap[u].x);
            float2 s23 = h2f(nap[u].y);
            float2 s4_ = h2f(nap[u].z);
            float2 e01 = h2f(r[u].y);
            float2 e23 = h2f(r[u].z);
            float a0 = s01.x, a1 = s01.y, a2 = s23.x, a3 = s23.y, a4 = s4_.x;
            float e0 = e01.x, e1 = e01.y, e2 = e23.x, e3 = e23.y;

            const float* pr = &pdl[dl * 12];
            float4 p0 = *reinterpret_cast<const float4*>(pr);
            float4 p1 = *reinterpret_cast<const float4*>(pr + 4);
            float2 p2 = *reinterpret_cast<const float2*>(pr + 8);
            float m[DM] = {p0.x, p0.y, p0.z, p0.w, p1.x, p1.y, p1.z, p1.w, p2.x, p2.y};
#pragma unroll
            for (int q = 0; q < DM; ++q) {
                float v = m[q];
                v = fmaf(a0, sws[q],      v);
                v = fmaf(a1, sws[10 + q], v);
                v = fmaf(a2, sws[20 + q], v);
                v = fmaf(a3, sws[30 + q], v);
                v = fmaf(a4, sws[40 + q], v);
                v = fmaf(e0, swe[q],      v);
                v = fmaf(e1, swe[10 + q], v);
                v = fmaf(e2, swe[20 + q], v);
                v = fmaf(e3, swe[30 + q], v);
                if (v > 0.f) atomicAdd(&acc[dl * DM + q], v);  // ds_add_f32
            }
        }
    }
    __syncthreads();

    float* dst = xpart + (size_t)sp * xstride + (size_t)nb0 * DM;
    for (int i = t; i < BKT_NODES * DM; i += 256)
        __builtin_nontemporal_store(acc[i], dst + i);
}

// ---------------------------------------------------------------------------
// C: combine partials + node-MLP head + wave-segmented pooling into gacc
// ---------------------------------------------------------------------------
__global__ __launch_bounds__(256) void combine_kernel(
    const float* __restrict__ xpart, size_t xstride,
    const int* __restrict__ batch,
    const float* __restrict__ w1, const float* __restrict__ b1,
    const float* __restrict__ w2, const float* __restrict__ b2,
    float* __restrict__ gacc, int N, int nsplit)
{
    __shared__ float s1[100], sb1[10], s2[50], sb2[5];
    int t = threadIdx.x;
    if (t < 100)      s1[t] = w1[t];
    else if (t < 110) sb1[t - 100] = b1[t - 100];
    else if (t < 160) s2[t - 110] = w2[t - 110];
    else if (t < 165) sb2[t - 160] = b2[t - 160];
    __syncthreads();

    int n = blockIdx.x * blockDim.x + t;
    bool valid = (n < N);
    int g = 0x7fffffff;
    float h2v[5] = {0.f, 0.f, 0.f, 0.f, 0.f};

    if (valid) {
        float x[DM];
#pragma unroll
        for (int q = 0; q < DM; ++q) x[q] = 0.f;
        for (int sp = 0; sp < nsplit; ++sp) {
            const float2* row = reinterpret_cast<const float2*>(
                xpart + (size_t)sp * xstride + (size_t)n * DM);
#pragma unroll
            for (int h = 0; h < 5; ++h) {
                float2 v = row[h];
                x[2 * h] += v.x; x[2 * h + 1] += v.y;
            }
        }

        float h1[10];
#pragma unroll
        for (int q = 0; q < 10; ++q) h1[q] = sb1[q];
#pragma unroll
        for (int k = 0; k < 10; ++k)
#pragma unroll
            for (int q = 0; q < 10; ++q) h1[q] = fmaf(x[k], s1[k * 10 + q], h1[q]);
#pragma unroll
        for (int q = 0; q < 10; ++q) h1[q] = fmaxf(h1[q], 0.f);
#pragma unroll
        for (int q = 0; q < 5; ++q) h2v[q] = sb2[q];
#pragma unroll
        for (int k = 0; k < 10; ++k)
#pragma unroll
            for (int q = 0; q < 5; ++q) h2v[q] = fmaf(h1[k], s2[k * 5 + q], h2v[q]);
#pragma unroll
        for (int q = 0; q < 5; ++q) h2v[q] = fmaxf(h2v[q], 0.f);
        g = batch[n];
    }

    int lane = t & 63;
#pragma unroll
    for (int o = 1; o < 64; o <<= 1) {
        int go = __shfl_down(g, o);
        float v0 = __shfl_down(h2v[0], o);
        float v1 = __shfl_down(h2v[1], o);
        float v2 = __shfl_down(h2v[2], o);
        float v3 = __shfl_down(h2v[3], o);
        float v4 = __shfl_down(h2v[4], o);
        if (lane + o < 64 && go == g) {
            h2v[0] += v0; h2v[1] += v1; h2v[2] += v2; h2v[3] += v3; h2v[4] += v4;
        }
    }
    int gp = __shfl_up(g, 1);
    bool head = (lane == 0) || (gp != g);
    if (head && g != 0x7fffffff) {
#pragma unroll
        for (int q = 0; q < 5; ++q)
            if (h2v[q] != 0.f) unsafeAtomicAdd(&gacc[(size_t)g * 5 + q], h2v[q]);
    }
}

// ---------------------------------------------------------------------------
// k4: per-graph head
// ---------------------------------------------------------------------------
__global__ __launch_bounds__(256) void graph_head_kernel(
    const float* __restrict__ gacc,
    const float* __restrict__ w3, const float* __restrict__ b3,
    const float* __restrict__ w4, const float* __restrict__ b4,
    float* __restrict__ out, int G)
{
    __shared__ float s3[25], sb3[5], s4[5], sb4[1];
    int t = threadIdx.x;
    if (t < 25)       s3[t] = w3[t];
    else if (t < 30)  sb3[t - 25] = b3[t - 25];
    else if (t < 35)  s4[t - 30] = w4[t - 30];
    else if (t == 35) sb4[0] = b4[0];
    __syncthreads();

    int g = blockIdx.x * blockDim.x + t;
    if (g >= G) return;

    float x[5];
#pragma unroll
    for (int k = 0; k < 5; ++k) x[k] = gacc[(size_t)g * 5 + k];

    float o = sb4[0];
#pragma unroll
    for (int q = 0; q < 5; ++q) {
        float h = sb3[q];
#pragma unroll
        for (int k = 0; k < 5; ++k) h = fmaf(x[k], s3[k * 5 + q], h);
        h = fmaxf(h, 0.f);
        o = fmaf(h, s4[q], o);
    }
    out[g] = o;
}

// ---------------------------------------------------------------------------
extern "C" void kernel_launch(void* const* d_in, const int* in_sizes, int n_in,
                              void* d_out, int out_size, void* d_ws, size_t ws_size,
                              hipStream_t stream)
{
    const int*   ei        = (const int*)d_in[0];
    const float* node_attr = (const float*)d_in[1];
    const float* edge_attr = (const float*)d_in[2];
    const int*   batch     = (const int*)d_in[3];
    const float* w_mpl = (const float*)d_in[5];
    const float* b_mpl = (const float*)d_in[6];
    const float* w1    = (const float*)d_in[7];
    const float* b1    = (const float*)d_in[8];
    const float* w2    = (const float*)d_in[9];
    const float* b2    = (const float*)d_in[10];
    const float* w3    = (const float*)d_in[11];
    const float* b3    = (const float*)d_in[12];
    const float* w4    = (const float*)d_in[13];
    const float* b4    = (const float*)d_in[14];
    float* out = (float*)d_out;

    const int E = in_sizes[0] / 2;
    const int N = in_sizes[1] / DN;
    const int G = out_size;

    const int nbk   = (N + BKT_NODES - 1) / BKT_NODES;     // 782
    const int chunk = (E + NB - 1) / NB;                   // 3125

    // workspace layout (xpart aliases cnt: cnt is dead once scatter completes)
    char* p = (char*)d_ws;
    u4v*      rec      = (u4v*)p;      p += (size_t)E * 16;
    u4v*      naph     = (u4v*)p;      p += (size_t)N * 16;
    unsigned* rowtotal = (unsigned*)p; p += ((size_t)nbk * 4 + 15) & ~15ull;
    unsigned* gbase    = (unsigned*)p; p += ((size_t)(nbk + 1) * 4 + 15) & ~15ull;
    float*    gacc     = (float*)p;    p += (size_t)G * 5 * 4;
    unsigned* cnt      = (unsigned*)p;
    float*    xpart    = (float*)p;    // same base as cnt (sequential reuse)
    size_t cnt_bytes = (size_t)nbk * NB * 4;

    // pick nsplit per available workspace (deterministic in ws_size)
    size_t used = (size_t)((char*)cnt - (char*)d_ws);
    size_t xstride = (size_t)nbk * BKT_NODES * DM;         // floats per split
    int nsplit = 8;
    while (nsplit > 1 &&
           used + ((cnt_bytes > (size_t)nsplit * xstride * 4) ? cnt_bytes
                                                              : (size_t)nsplit * xstride * 4) > ws_size)
        nsplit >>= 1;

    hipMemsetAsync(gacc, 0, (size_t)G * 5 * 4, stream);

    hist_pack_kernel<<<NB, 256, 0, stream>>>(ei, node_attr, naph, cnt, E, chunk, nbk, N);
    scan_rows_kernel<<<nbk, 256, 0, stream>>>(cnt, rowtotal);
    scan_base_kernel<<<1, 1024, 0, stream>>>(rowtotal, gbase, nbk, E);
    scatter_kernel<<<NB, 256, 0, stream>>>(ei, edge_attr, cnt, gbase, rec, E, chunk, nbk);
    gather_kernel<<<nbk * nsplit, 256, 0, stream>>>(rec, gbase, naph, w_mpl, b_mpl,
                                                    xpart, xstride, E, N, nbk, nsplit);
    combine_kernel<<<nbk, 256, 0, stream>>>(xpart, xstride, batch, w1, b1, w2, b2, gacc, N, nsplit);
    graph_head_kernel<<<(G + 255) / 256, 256, 0, stream>>>(gacc, w3, b3, w4, b4, out, G);
}